// Round 1
// baseline (19898.340 us; speedup 1.0000x reference)
//
#include <hip/hip_runtime.h>
#include <hip/hip_cooperative_groups.h>
#include <stdint.h>

namespace cg = cooperative_groups;

#define T_STEPS 512
#define NB 64
#define HID 1024
#define G4 4096

typedef __attribute__((ext_vector_type(8))) short bf16x8;
typedef __attribute__((ext_vector_type(4))) float f32x4;

__device__ inline unsigned short f2bf(float f) {
  unsigned int u = __float_as_uint(f);
  return (unsigned short)((u + 0x7fffu + ((u >> 16) & 1u)) >> 16);
}
__device__ inline unsigned int pack2bf(float lo, float hi) {
  return (unsigned int)f2bf(lo) | ((unsigned int)f2bf(hi) << 16);
}

// ---------------- fp32 -> bf16 conversion (for W_hh) ----------------
__global__ __launch_bounds__(256) void cvt_bf16_kernel(const float4* __restrict__ src,
                                                       ushort4* __restrict__ dst) {
  int i = blockIdx.x * 256 + threadIdx.x;
  float4 v = src[i];
  ushort4 r;
  r.x = f2bf(v.x); r.y = f2bf(v.y); r.z = f2bf(v.z); r.w = f2bf(v.w);
  dst[i] = r;
}

// ---------------- zero-init c-state and h double buffer ----------------
__global__ __launch_bounds__(256) void init_state_kernel(float* __restrict__ c_state,
                                                         unsigned short* __restrict__ h_buf) {
  int i = blockIdx.x * 256 + threadIdx.x;   // 0..131071
  if (i < NB * HID) c_state[i] = 0.0f;
  h_buf[i] = 0;                              // covers both h buffers (2*64*1024)
}

// ---------------- phase 1 (chunked): xp_c = x[:, t0:t0+TC] @ W_ih^T + bias ----------------
#define BM 128
#define BN 128
#define BK 32
#define LDT 72   // LDS row stride (bf16 elems); 144B rows keep 16B alignment

__global__ __launch_bounds__(256, 2) void gemm_xproj_chunk(
    const float* __restrict__ x,      // [64*512][1024] fp32
    const float* __restrict__ Wih,    // [4096][1024] fp32
    const float* __restrict__ b_ih,
    const float* __restrict__ b_hh,
    float* __restrict__ Cc,           // [64*TC][4096] fp32
    int t0, int tclog2) {
  __shared__ unsigned short As[BM * LDT];
  __shared__ unsigned short Bs[BN * LDT];
  const int tid = threadIdx.x;
  const int m0 = blockIdx.x * BM;
  const int n0 = blockIdx.y * BN;
  const int wave = tid >> 6, lane = tid & 63;
  const int wm = (wave & 1) * 64, wn = (wave >> 1) * 64;
  const int lq = lane >> 4, lr = lane & 15;
  const int srow = tid >> 1;
  const int scol = (tid & 1) * 16;
  const int am = m0 + srow;
  const int ab = am >> tclog2, adt = am & ((1 << tclog2) - 1);
  const float* arow = x + (size_t)(ab * 512 + t0 + adt) * 1024 + scol;
  const float* brow = Wih + (size_t)(n0 + srow) * 1024 + scol;
  unsigned short* asd = As + srow * LDT + scol;
  unsigned short* bsd = Bs + srow * LDT + scol;
  f32x4 acc[4][4] = {};
  for (int kk = 0; kk < 1024; kk += BK) {
    float4 a0 = *(const float4*)(arow + kk);
    float4 a1 = *(const float4*)(arow + kk + 4);
    float4 a2 = *(const float4*)(arow + kk + 8);
    float4 a3 = *(const float4*)(arow + kk + 12);
    float4 w0 = *(const float4*)(brow + kk);
    float4 w1 = *(const float4*)(brow + kk + 4);
    float4 w2 = *(const float4*)(brow + kk + 8);
    float4 w3 = *(const float4*)(brow + kk + 12);
    __syncthreads();
    uint4 pa0, pa1, pb0, pb1;
    pa0.x = pack2bf(a0.x, a0.y); pa0.y = pack2bf(a0.z, a0.w);
    pa0.z = pack2bf(a1.x, a1.y); pa0.w = pack2bf(a1.z, a1.w);
    pa1.x = pack2bf(a2.x, a2.y); pa1.y = pack2bf(a2.z, a2.w);
    pa1.z = pack2bf(a3.x, a3.y); pa1.w = pack2bf(a3.z, a3.w);
    pb0.x = pack2bf(w0.x, w0.y); pb0.y = pack2bf(w0.z, w0.w);
    pb0.z = pack2bf(w1.x, w1.y); pb0.w = pack2bf(w1.z, w1.w);
    pb1.x = pack2bf(w2.x, w2.y); pb1.y = pack2bf(w2.z, w2.w);
    pb1.z = pack2bf(w3.x, w3.y); pb1.w = pack2bf(w3.z, w3.w);
    *(uint4*)(asd) = pa0; *(uint4*)(asd + 8) = pa1;
    *(uint4*)(bsd) = pb0; *(uint4*)(bsd + 8) = pb1;
    __syncthreads();
    bf16x8 af[4], bfr[4];
    #pragma unroll
    for (int i = 0; i < 4; ++i) {
      af[i]  = *(const bf16x8*)(As + (wm + i * 16 + lr) * LDT + lq * 8);
      bfr[i] = *(const bf16x8*)(Bs + (wn + i * 16 + lr) * LDT + lq * 8);
    }
    #pragma unroll
    for (int mt = 0; mt < 4; ++mt)
      #pragma unroll
      for (int nt = 0; nt < 4; ++nt)
        acc[mt][nt] = __builtin_amdgcn_mfma_f32_16x16x32_bf16(af[mt], bfr[nt], acc[mt][nt], 0, 0, 0);
  }
  #pragma unroll
  for (int nt = 0; nt < 4; ++nt) {
    int col = n0 + wn + nt * 16 + lr;
    float bias = b_ih[col] + b_hh[col];
    #pragma unroll
    for (int mt = 0; mt < 4; ++mt) {
      int rb = m0 + wm + mt * 16 + lq * 4;
      #pragma unroll
      for (int r = 0; r < 4; ++r)
        Cc[(size_t)(rb + r) * G4 + col] = acc[mt][nt][r] + bias;
    }
  }
}

// ---------------- phase 2: persistent cooperative step loop ----------------
// 256 blocks x 256 thr, 1 block/CU. Block bid: g = bid&3 (batch group, 16 rows),
// u = bid>>2 (hidden units [16u,16u+16)). Wave = gate (0=f,1=i,2=o,3=g).
// W_hh fragments register-resident for the whole chunk; c-state register-resident;
// h double-buffered in global, grid.sync() between steps.
__global__ __launch_bounds__(256, 1) void lstm_steps_coop(
    const unsigned short* __restrict__ Whh,   // bf16 [4096][1024]
    const float* __restrict__ xc,             // chunk [64*TC][4096] fp32
    unsigned short* __restrict__ h_buf,       // bf16 2x[64][1024] double buffer
    float* __restrict__ c_state,              // fp32 [64][1024]
    float* __restrict__ out,                  // fp32 [64*512][1024]
    int t0, int tc, int tclog2) {
  cg::grid_group grid = cg::this_grid();
  __shared__ float gb[4][16][16];             // activated gates (4KB)
  const int tid = threadIdx.x;
  const int bid = blockIdx.x;
  const int g = bid & 3;                      // batch group: rows [16g,16g+16)
  const int u = bid >> 2;                     // unit group: cols [16u,16u+16)
  const int wave = tid >> 6, lane = tid & 63;
  const int lq = lane >> 4, lr = lane & 15;
  const int rowbase = wave * HID + u * 16;    // W_hh row block for this wave's gate

  // register-resident W_hh fragments (128 VGPRs), loaded ONCE per chunk
  const unsigned short* wrow = Whh + (size_t)(rowbase + lr) * HID + lq * 8;
  bf16x8 wf[32];
  #pragma unroll
  for (int kk = 0; kk < 32; ++kk) wf[kk] = *(const bf16x8*)(wrow + kk * 32);

  // register-resident cell state for this thread's (batch,unit)
  const int bl = tid >> 4, nl = tid & 15;
  const int ci = (g * 16 + bl) * HID + u * 16 + nl;
  float c_val = c_state[ci];

  for (int dt = 0; dt < tc; ++dt) {
    const int t = t0 + dt;
    const unsigned short* hin = h_buf + (size_t)(t & 1) * (NB * HID)
                                + (size_t)(g * 16 + lr) * HID + lq * 8;
    f32x4 accA = {}, accB = {};
    #pragma unroll
    for (int kk = 0; kk < 32; kk += 2) {
      bf16x8 a0 = *(const bf16x8*)(hin + kk * 32);
      bf16x8 a1 = *(const bf16x8*)(hin + kk * 32 + 32);
      accA = __builtin_amdgcn_mfma_f32_16x16x32_bf16(a0, wf[kk], accA, 0, 0, 0);
      accB = __builtin_amdgcn_mfma_f32_16x16x32_bf16(a1, wf[kk + 1], accB, 0, 0, 0);
    }
    f32x4 a = accA + accB;
    #pragma unroll
    for (int r = 0; r < 4; ++r) {
      int brow = g * 16 + lq * 4 + r;
      float pre = a[r] + xc[(size_t)((brow << tclog2) + dt) * G4 + rowbase + lr];
      float v;
      if (wave == 3) v = 2.0f / (1.0f + __expf(-2.0f * pre)) - 1.0f;  // tanh
      else           v = 1.0f / (1.0f + __expf(-pre));                 // sigmoid
      gb[wave][lq * 4 + r][lr] = v;
    }
    __syncthreads();
    {
      float f = gb[0][bl][nl], i = gb[1][bl][nl], o = gb[2][bl][nl], gg = gb[3][bl][nl];
      c_val = f * c_val + i * gg;
      float th = 2.0f / (1.0f + __expf(-2.0f * c_val));
      th = th - 1.0f;
      float h = o * th;
      out[((size_t)(g * 16 + bl) * T_STEPS + t) * HID + u * 16 + nl] = h;
      h_buf[(size_t)((t + 1) & 1) * (NB * HID) + (size_t)(g * 16 + bl) * HID + u * 16 + nl] = f2bf(h);
    }
    if (dt + 1 < tc) grid.sync();
  }
  c_state[ci] = c_val;
}

extern "C" void kernel_launch(void* const* d_in, const int* in_sizes, int n_in,
                              void* d_out, int out_size, void* d_ws, size_t ws_size,
                              hipStream_t stream) {
  const float* x    = (const float*)d_in[0];
  const float* W_ih = (const float*)d_in[1];
  const float* W_hh = (const float*)d_in[2];
  const float* b_ih = (const float*)d_in[3];
  const float* b_hh = (const float*)d_in[4];
  float* out = (float*)d_out;
  char* ws = (char*)d_ws;

  // fixed allocations: bf16 W_hh (8MB) + c_state (256KB) + h double buffer (256KB)
  const size_t whh_bytes = (size_t)G4 * HID * 2;
  const size_t c_bytes   = (size_t)NB * HID * 4;
  const size_t h_bytes   = (size_t)2 * NB * HID * 2;
  const size_t fixed = whh_bytes + c_bytes + h_bytes;
  // adaptive time-chunk: largest TC in {64..2} whose fp32 chunk buffer fits
  int tclog2 = 6;
  while (tclog2 > 1) {
    size_t need = fixed + (((size_t)NB << tclog2) * G4 * 4);
    if (need <= ws_size) break;
    --tclog2;
  }
  const int TC = 1 << tclog2;

  size_t off = 0;
  float* chunk = (float*)(ws + off);                  off += ((size_t)NB << tclog2) * G4 * 4;
  unsigned short* whhb = (unsigned short*)(ws + off); off += whh_bytes;
  float* c_state = (float*)(ws + off);                off += c_bytes;
  unsigned short* h_buf = (unsigned short*)(ws + off);

  init_state_kernel<<<512, 256, 0, stream>>>(c_state, h_buf);
  cvt_bf16_kernel<<<4096, 256, 0, stream>>>((const float4*)W_hh, (ushort4*)whhb);

  const int n_chunks = T_STEPS >> tclog2;
  for (int c = 0; c < n_chunks; ++c) {
    const int t0 = c << tclog2;
    gemm_xproj_chunk<<<dim3(TC / 2, 32), 256, 0, stream>>>(x, W_ih, b_ih, b_hh,
                                                           chunk, t0, tclog2);
    int t0v = t0, tcv = TC, tlv = tclog2;
    void* args[] = {(void*)&whhb, (void*)&chunk, (void*)&h_buf, (void*)&c_state,
                    (void*)&out, (void*)&t0v, (void*)&tcv, (void*)&tlv};
    hipLaunchCooperativeKernel((const void*)lstm_steps_coop, dim3(256), dim3(256),
                               args, 0, stream);
  }
}

// Round 4
// 6178.421 us; speedup vs baseline: 3.2206x; 3.2206x over previous
//
#include <hip/hip_runtime.h>
#include <stdint.h>

#define T_STEPS 512
#define NB 64
#define HID 1024
#define G4 4096

typedef __attribute__((ext_vector_type(8))) short bf16x8;
typedef __attribute__((ext_vector_type(4))) float f32x4;
typedef __attribute__((ext_vector_type(4))) unsigned int u32x4;

__device__ inline unsigned short f2bf(float f) {
  unsigned int u = __float_as_uint(f);
  return (unsigned short)((u + 0x7fffu + ((u >> 16) & 1u)) >> 16);
}
__device__ inline unsigned int pack2bf(float lo, float hi) {
  return (unsigned int)f2bf(lo) | ((unsigned int)f2bf(hi) << 16);
}

// ---------------- fp32 -> bf16 conversion (for W_hh) ----------------
__global__ __launch_bounds__(256) void cvt_bf16_kernel(const float4* __restrict__ src,
                                                       ushort4* __restrict__ dst) {
  int i = blockIdx.x * 256 + threadIdx.x;
  float4 v = src[i];
  ushort4 r;
  r.x = f2bf(v.x); r.y = f2bf(v.y); r.z = f2bf(v.z); r.w = f2bf(v.w);
  dst[i] = r;
}

// ---------------- zero-init c-state, h ring slot 0, barrier counters ----------------
__global__ __launch_bounds__(256) void init_state_kernel(float* __restrict__ c_state,
                                                         unsigned* __restrict__ hist32,
                                                         unsigned* __restrict__ bar) {
  int i = blockIdx.x * 256 + threadIdx.x;   // 0..131071
  if (i < NB * HID) c_state[i] = 0.0f;
  if (i < 32768) hist32[i] = 0u;             // ring slot 0 = h(0) = 0
  if (i < 128) bar[i] = 0u;
}

// ---------------- phase 1 (chunked): xp_c = x[:, t0:t0+TC] @ W_ih^T + bias ----------------
#define BM 128
#define BN 128
#define BK 32
#define LDT 72   // LDS row stride (bf16 elems); 144B rows keep 16B alignment

__global__ __launch_bounds__(256, 2) void gemm_xproj_chunk(
    const float* __restrict__ x,      // [64*512][1024] fp32
    const float* __restrict__ Wih,    // [4096][1024] fp32
    const float* __restrict__ b_ih,
    const float* __restrict__ b_hh,
    float* __restrict__ Cc,           // [64*TC][4096] fp32
    int t0, int tclog2) {
  __shared__ unsigned short As[BM * LDT];
  __shared__ unsigned short Bs[BN * LDT];
  const int tid = threadIdx.x;
  const int m0 = blockIdx.x * BM;
  const int n0 = blockIdx.y * BN;
  const int wave = tid >> 6, lane = tid & 63;
  const int wm = (wave & 1) * 64, wn = (wave >> 1) * 64;
  const int lq = lane >> 4, lr = lane & 15;
  const int srow = tid >> 1;
  const int scol = (tid & 1) * 16;
  const int am = m0 + srow;
  const int ab = am >> tclog2, adt = am & ((1 << tclog2) - 1);
  const float* arow = x + (size_t)(ab * 512 + t0 + adt) * 1024 + scol;
  const float* brow = Wih + (size_t)(n0 + srow) * 1024 + scol;
  unsigned short* asd = As + srow * LDT + scol;
  unsigned short* bsd = Bs + srow * LDT + scol;
  f32x4 acc[4][4] = {};
  for (int kk = 0; kk < 1024; kk += BK) {
    float4 a0 = *(const float4*)(arow + kk);
    float4 a1 = *(const float4*)(arow + kk + 4);
    float4 a2 = *(const float4*)(arow + kk + 8);
    float4 a3 = *(const float4*)(arow + kk + 12);
    float4 w0 = *(const float4*)(brow + kk);
    float4 w1 = *(const float4*)(brow + kk + 4);
    float4 w2 = *(const float4*)(brow + kk + 8);
    float4 w3 = *(const float4*)(brow + kk + 12);
    __syncthreads();
    uint4 pa0, pa1, pb0, pb1;
    pa0.x = pack2bf(a0.x, a0.y); pa0.y = pack2bf(a0.z, a0.w);
    pa0.z = pack2bf(a1.x, a1.y); pa0.w = pack2bf(a1.z, a1.w);
    pa1.x = pack2bf(a2.x, a2.y); pa1.y = pack2bf(a2.z, a2.w);
    pa1.z = pack2bf(a3.x, a3.y); pa1.w = pack2bf(a3.z, a3.w);
    pb0.x = pack2bf(w0.x, w0.y); pb0.y = pack2bf(w0.z, w0.w);
    pb0.z = pack2bf(w1.x, w1.y); pb0.w = pack2bf(w1.z, w1.w);
    pb1.x = pack2bf(w2.x, w2.y); pb1.y = pack2bf(w2.z, w2.w);
    pb1.z = pack2bf(w3.x, w3.y); pb1.w = pack2bf(w3.z, w3.w);
    *(uint4*)(asd) = pa0; *(uint4*)(asd + 8) = pa1;
    *(uint4*)(bsd) = pb0; *(uint4*)(bsd + 8) = pb1;
    __syncthreads();
    bf16x8 af[4], bfr[4];
    #pragma unroll
    for (int i = 0; i < 4; ++i) {
      af[i]  = *(const bf16x8*)(As + (wm + i * 16 + lr) * LDT + lq * 8);
      bfr[i] = *(const bf16x8*)(Bs + (wn + i * 16 + lr) * LDT + lq * 8);
    }
    #pragma unroll
    for (int mt = 0; mt < 4; ++mt)
      #pragma unroll
      for (int nt = 0; nt < 4; ++nt)
        acc[mt][nt] = __builtin_amdgcn_mfma_f32_16x16x32_bf16(af[mt], bfr[nt], acc[mt][nt], 0, 0, 0);
  }
  #pragma unroll
  for (int nt = 0; nt < 4; ++nt) {
    int col = n0 + wn + nt * 16 + lr;
    float bias = b_ih[col] + b_hh[col];
    #pragma unroll
    for (int mt = 0; mt < 4; ++mt) {
      int rb = m0 + wm + mt * 16 + lq * 4;
      #pragma unroll
      for (int r = 0; r < 4; ++r)
        Cc[(size_t)(rb + r) * G4 + col] = acc[mt][nt][r] + bias;
    }
  }
}

// ---------------- phase 2: persistent step loop, per-group barriers ----------------
// 256 blocks x 256 thr (cooperative, 1 block/CU). Block: grp = bid&3 (batches
// [16*grp,16*grp+16)), u = bid>>2 (hidden units [16u,16u+16)). Wave = gate.
// Coherence design (no unverified sc-bit semantics in the correctness chain):
//   - h history RING: slot dt holds h(t0+dt); no address is read twice within a
//     kernel, so stale L2 lines cannot be consumed (cold miss -> MALL).
//   - h publish = no-return __hip_atomic_exchange (executes AT the MALL; m20-
//     verified cross-XCD). Compiler-tracked -> the vmcnt(0) before S3's
//     s_barrier drains swaps before tid0's arrival atomicAdd.
//   - per-group epoch barrier: cumulative counter, arrivals via atomicAdd,
//     spin via sc0 sc1 load (release mechanism only).
__global__ __launch_bounds__(256, 1) void lstm_steps_coop(
    const unsigned short* __restrict__ Whh,   // bf16 [4096][1024]
    const float* __restrict__ xc,             // chunk [64*TC][4096] fp32
    unsigned* __restrict__ hist32,            // h ring: (TC+1) x [64][1024] bf16
    float* __restrict__ c_state,              // fp32 [64][1024]
    float* __restrict__ out,                  // fp32 [64*512][1024]
    unsigned* __restrict__ bar,               // 4 counters, 128B apart
    int t0, int tc, int tclog2, int ep0) {
  __shared__ char hs[32768] __attribute__((aligned(16)));  // h tile [16][1024] bf16, swizzled
  __shared__ float gb[4][16][16];                          // activated gates
  const int tid = threadIdx.x;
  const int bid = blockIdx.x;
  const int grp = bid & 3;
  const int u = bid >> 2;
  const int wave = tid >> 6, lane = tid & 63;
  const int lq = lane >> 4, lr = lane & 15;
  const int rowbase = wave * HID + u * 16;
  const unsigned short* wrow = Whh + (size_t)(rowbase + lr) * HID + lq * 8;
  // loader mapping: thread t covers row t>>4, 16B col-slot t&15, 8 slots 256B apart
  const int srow = tid >> 4, scq = tid & 15;
  const char* gsrc_base = (const char*)hist32 + (size_t)(grp * 16 + srow) * 2048 + scq * 16;
  const int lds_base = srow * 2048 + scq * 16;
  const int lswz = (srow & 7) << 4;
  // MFMA A-frag read base (same XOR per row)
  const int abase = lr * 2048 + lq * 16;
  const int aswz = (lr & 7) << 4;
  unsigned* barp = bar + grp * 32;
  // epilogue mapping (tid<128): (batch eb, units 2*np,2*np+1); c register-resident
  const int eb = tid >> 3, np = tid & 7;
  const size_t cidx = (size_t)(grp * 16 + eb) * HID + u * 16 + np * 2;
  const int hoff = (grp * 16 + eb) * 512 + u * 8 + np;   // u32 index within a ring slot
  float c0 = 0.f, c1 = 0.f;
  if (tid < 128) { float2 cv = *(const float2*)(c_state + cidx); c0 = cv.x; c1 = cv.y; }

  for (int dt = 0; dt < tc; ++dt) {
    const int t = t0 + dt;
    // ---- stage h(t) from ring slot dt into LDS ----
    {
      const char* src = gsrc_base + (size_t)dt * 131072;
      u32x4 v0, v1, v2, v3, v4, v5, v6, v7;
      asm volatile("global_load_dwordx4 %0, %1, off sc0 sc1" : "=v"(v0) : "v"(src +    0) : "memory");
      asm volatile("global_load_dwordx4 %0, %1, off sc0 sc1" : "=v"(v1) : "v"(src +  256) : "memory");
      asm volatile("global_load_dwordx4 %0, %1, off sc0 sc1" : "=v"(v2) : "v"(src +  512) : "memory");
      asm volatile("global_load_dwordx4 %0, %1, off sc0 sc1" : "=v"(v3) : "v"(src +  768) : "memory");
      asm volatile("global_load_dwordx4 %0, %1, off sc0 sc1" : "=v"(v4) : "v"(src + 1024) : "memory");
      asm volatile("global_load_dwordx4 %0, %1, off sc0 sc1" : "=v"(v5) : "v"(src + 1280) : "memory");
      asm volatile("global_load_dwordx4 %0, %1, off sc0 sc1" : "=v"(v6) : "v"(src + 1536) : "memory");
      asm volatile("global_load_dwordx4 %0, %1, off sc0 sc1" : "=v"(v7) : "v"(src + 1792) : "memory");
      asm volatile("s_waitcnt vmcnt(0)" ::: "memory");
      __builtin_amdgcn_sched_barrier(0);
      *(u32x4*)(hs + ((lds_base +    0) ^ lswz)) = v0;
      *(u32x4*)(hs + ((lds_base +  256) ^ lswz)) = v1;
      *(u32x4*)(hs + ((lds_base +  512) ^ lswz)) = v2;
      *(u32x4*)(hs + ((lds_base +  768) ^ lswz)) = v3;
      *(u32x4*)(hs + ((lds_base + 1024) ^ lswz)) = v4;
      *(u32x4*)(hs + ((lds_base + 1280) ^ lswz)) = v5;
      *(u32x4*)(hs + ((lds_base + 1536) ^ lswz)) = v6;
      *(u32x4*)(hs + ((lds_base + 1792) ^ lswz)) = v7;
    }
    __syncthreads();   // S1: h staged
    // ---- gate pre-activations: 32 MFMAs per wave ----
    f32x4 accA = {}, accB = {};
    #pragma unroll
    for (int kk = 0; kk < 32; kk += 2) {
      bf16x8 a0 = *(const bf16x8*)(hs + ((abase + kk * 64) ^ aswz));
      bf16x8 a1 = *(const bf16x8*)(hs + ((abase + kk * 64 + 64) ^ aswz));
      bf16x8 w0 = *(const bf16x8*)(wrow + kk * 32);
      bf16x8 w1 = *(const bf16x8*)(wrow + kk * 32 + 32);
      accA = __builtin_amdgcn_mfma_f32_16x16x32_bf16(a0, w0, accA, 0, 0, 0);
      accB = __builtin_amdgcn_mfma_f32_16x16x32_bf16(a1, w1, accB, 0, 0, 0);
    }
    f32x4 a = accA + accB;
    #pragma unroll
    for (int r = 0; r < 4; ++r) {
      int brow = grp * 16 + lq * 4 + r;
      float pre = a[r] + xc[(size_t)((brow << tclog2) + dt) * G4 + rowbase + lr];
      float v;
      if (wave == 3) v = 2.0f / (1.0f + __expf(-2.0f * pre)) - 1.0f;  // tanh
      else           v = 1.0f / (1.0f + __expf(-pre));                 // sigmoid
      gb[wave][lq * 4 + r][lr] = v;
    }
    __syncthreads();   // S2: gates ready
    // ---- cell update + h publish (atomic swap executes at MALL) ----
    if (tid < 128) {
      float2 fv = *(const float2*)&gb[0][eb][np * 2];
      float2 iv = *(const float2*)&gb[1][eb][np * 2];
      float2 ov = *(const float2*)&gb[2][eb][np * 2];
      float2 gv = *(const float2*)&gb[3][eb][np * 2];
      c0 = fv.x * c0 + iv.x * gv.x;
      c1 = fv.y * c1 + iv.y * gv.y;
      float h0 = ov.x * (2.0f / (1.0f + __expf(-2.0f * c0)) - 1.0f);
      float h1 = ov.y * (2.0f / (1.0f + __expf(-2.0f * c1)) - 1.0f);
      *(float2*)(out + ((size_t)(grp * 16 + eb) * T_STEPS + t) * HID + u * 16 + np * 2)
          = make_float2(h0, h1);
      unsigned hv = pack2bf(h0, h1);
      (void)__hip_atomic_exchange(hist32 + (size_t)(dt + 1) * 32768 + hoff, hv,
                                  __ATOMIC_RELAXED, __HIP_MEMORY_SCOPE_AGENT);
      if (dt == tc - 1)   // hand-off: next chunk reads its h(t0) from slot 0
        (void)__hip_atomic_exchange(hist32 + hoff, hv,
                                    __ATOMIC_RELAXED, __HIP_MEMORY_SCOPE_AGENT);
    }
    if (dt != tc - 1) {
      __syncthreads();   // S3: swaps drained (vmcnt(0) before s_barrier)
      // ---- per-group epoch barrier: 64 arrivals/step, cumulative count ----
      if (tid == 0) {
        atomicAdd(barp, 1u);
        const unsigned target = 64u * (unsigned)(ep0 + dt + 1);
        unsigned cnt;
        for (;;) {
          asm volatile("global_load_dword %0, %1, off sc0 sc1\n\ts_waitcnt vmcnt(0)"
                       : "=v"(cnt) : "v"(barp) : "memory");
          if (cnt >= target) break;
          __builtin_amdgcn_s_sleep(1);
        }
      }
      __syncthreads();   // S4: release
    }
  }
  if (tid < 128) *(float2*)(c_state + cidx) = make_float2(c0, c1);
}

extern "C" void kernel_launch(void* const* d_in, const int* in_sizes, int n_in,
                              void* d_out, int out_size, void* d_ws, size_t ws_size,
                              hipStream_t stream) {
  const float* x    = (const float*)d_in[0];
  const float* W_ih = (const float*)d_in[1];
  const float* W_hh = (const float*)d_in[2];
  const float* b_ih = (const float*)d_in[3];
  const float* b_hh = (const float*)d_in[4];
  float* out = (float*)d_out;
  char* ws = (char*)d_ws;

  const size_t whh_bytes = (size_t)G4 * HID * 2;     // 8 MB
  const size_t c_bytes   = (size_t)NB * HID * 4;     // 256 KB
  const size_t bar_bytes = 512;
  // adaptive time-chunk: largest TC in {64..4} s.t. chunk fp32 + h ring fit
  int tclog2 = 6;
  while (tclog2 > 1) {
    const size_t hist_b = ((size_t)(1 << tclog2) + 1) * (NB * HID * 2);
    size_t need = whh_bytes + c_bytes + bar_bytes + hist_b
                + (((size_t)NB << tclog2) * G4 * 4);
    if (need <= ws_size) break;
    --tclog2;
  }
  const int TC = 1 << tclog2;
  const size_t hist_bytes = ((size_t)TC + 1) * (NB * HID * 2);

  size_t off = 0;
  float* chunk = (float*)(ws + off);                  off += ((size_t)NB << tclog2) * G4 * 4;
  unsigned short* whhb = (unsigned short*)(ws + off); off += whh_bytes;
  float* c_state = (float*)(ws + off);                off += c_bytes;
  unsigned* hist32 = (unsigned*)(ws + off);           off += hist_bytes;
  unsigned* bar = (unsigned*)(ws + off);

  init_state_kernel<<<512, 256, 0, stream>>>(c_state, hist32, bar);
  cvt_bf16_kernel<<<4096, 256, 0, stream>>>((const float4*)W_hh, (ushort4*)whhb);

  const int n_chunks = T_STEPS >> tclog2;
  for (int c = 0; c < n_chunks; ++c) {
    const int t0 = c << tclog2;
    gemm_xproj_chunk<<<dim3(TC / 2, 32), 256, 0, stream>>>(x, W_ih, b_ih, b_hh,
                                                           chunk, t0, tclog2);
    int t0v = t0, tcv = TC, tlv = tclog2;
    int ep0 = c * (TC - 1);   // barriered steps before this chunk
    void* args[] = {(void*)&whhb, (void*)&chunk, (void*)&hist32, (void*)&c_state,
                    (void*)&out, (void*)&bar, (void*)&t0v, (void*)&tcv, (void*)&tlv,
                    (void*)&ep0};
    hipLaunchCooperativeKernel((const void*)lstm_steps_coop, dim3(256), dim3(256),
                               args, 0, stream);
  }
}

// Round 5
// 2571.105 us; speedup vs baseline: 7.7392x; 2.4030x over previous
//
#include <hip/hip_runtime.h>
#include <stdint.h>

#define T_STEPS 512
#define NB 64
#define HID 1024
#define G4 4096

typedef __attribute__((ext_vector_type(8))) short bf16x8;
typedef __attribute__((ext_vector_type(4))) float f32x4;
typedef __attribute__((ext_vector_type(4))) unsigned int u32x4;

__device__ inline unsigned short f2bf(float f) {
  unsigned int u = __float_as_uint(f);
  return (unsigned short)((u + 0x7fffu + ((u >> 16) & 1u)) >> 16);
}
__device__ inline unsigned int pack2bf(float lo, float hi) {
  return (unsigned int)f2bf(lo) | ((unsigned int)f2bf(hi) << 16);
}

// ---------------- fp32 -> bf16 conversion (for W_hh) ----------------
__global__ __launch_bounds__(256) void cvt_bf16_kernel(const float4* __restrict__ src,
                                                       ushort4* __restrict__ dst) {
  int i = blockIdx.x * 256 + threadIdx.x;
  float4 v = src[i];
  ushort4 r;
  r.x = f2bf(v.x); r.y = f2bf(v.y); r.z = f2bf(v.z); r.w = f2bf(v.w);
  dst[i] = r;
}

// ---------------- zero-init c-state, h ring slot 0, barrier counters ----------------
__global__ __launch_bounds__(256) void init_state_kernel(float* __restrict__ c_state,
                                                         unsigned* __restrict__ hist32,
                                                         unsigned* __restrict__ bar) {
  int i = blockIdx.x * 256 + threadIdx.x;   // 0..131071
  if (i < NB * HID) c_state[i] = 0.0f;
  if (i < 32768) hist32[i] = 0u;             // ring slot 0 = h(0) = 0
  if (i < 128) bar[i] = 0u;
}

// ---------------- phase 1 (chunked): xp_c = x[:, t0:t0+TC] @ W_ih^T + bias ----------------
#define BM 128
#define BN 128
#define BK 32
#define LDT 72   // LDS row stride (bf16 elems); 144B rows keep 16B alignment

__global__ __launch_bounds__(256, 2) void gemm_xproj_chunk(
    const float* __restrict__ x,      // [64*512][1024] fp32
    const float* __restrict__ Wih,    // [4096][1024] fp32
    const float* __restrict__ b_ih,
    const float* __restrict__ b_hh,
    float* __restrict__ Cc,           // [64*TC][4096] fp32
    int t0, int tclog2) {
  __shared__ unsigned short As[BM * LDT];
  __shared__ unsigned short Bs[BN * LDT];
  const int tid = threadIdx.x;
  const int m0 = blockIdx.x * BM;
  const int n0 = blockIdx.y * BN;
  const int wave = tid >> 6, lane = tid & 63;
  const int wm = (wave & 1) * 64, wn = (wave >> 1) * 64;
  const int lq = lane >> 4, lr = lane & 15;
  const int srow = tid >> 1;
  const int scol = (tid & 1) * 16;
  const int am = m0 + srow;
  const int ab = am >> tclog2, adt = am & ((1 << tclog2) - 1);
  const float* arow = x + (size_t)(ab * 512 + t0 + adt) * 1024 + scol;
  const float* brow = Wih + (size_t)(n0 + srow) * 1024 + scol;
  unsigned short* asd = As + srow * LDT + scol;
  unsigned short* bsd = Bs + srow * LDT + scol;
  f32x4 acc[4][4] = {};
  for (int kk = 0; kk < 1024; kk += BK) {
    float4 a0 = *(const float4*)(arow + kk);
    float4 a1 = *(const float4*)(arow + kk + 4);
    float4 a2 = *(const float4*)(arow + kk + 8);
    float4 a3 = *(const float4*)(arow + kk + 12);
    float4 w0 = *(const float4*)(brow + kk);
    float4 w1 = *(const float4*)(brow + kk + 4);
    float4 w2 = *(const float4*)(brow + kk + 8);
    float4 w3 = *(const float4*)(brow + kk + 12);
    __syncthreads();
    uint4 pa0, pa1, pb0, pb1;
    pa0.x = pack2bf(a0.x, a0.y); pa0.y = pack2bf(a0.z, a0.w);
    pa0.z = pack2bf(a1.x, a1.y); pa0.w = pack2bf(a1.z, a1.w);
    pa1.x = pack2bf(a2.x, a2.y); pa1.y = pack2bf(a2.z, a2.w);
    pa1.z = pack2bf(a3.x, a3.y); pa1.w = pack2bf(a3.z, a3.w);
    pb0.x = pack2bf(w0.x, w0.y); pb0.y = pack2bf(w0.z, w0.w);
    pb0.z = pack2bf(w1.x, w1.y); pb0.w = pack2bf(w1.z, w1.w);
    pb1.x = pack2bf(w2.x, w2.y); pb1.y = pack2bf(w2.z, w2.w);
    pb1.z = pack2bf(w3.x, w3.y); pb1.w = pack2bf(w3.z, w3.w);
    *(uint4*)(asd) = pa0; *(uint4*)(asd + 8) = pa1;
    *(uint4*)(bsd) = pb0; *(uint4*)(bsd + 8) = pb1;
    __syncthreads();
    bf16x8 af[4], bfr[4];
    #pragma unroll
    for (int i = 0; i < 4; ++i) {
      af[i]  = *(const bf16x8*)(As + (wm + i * 16 + lr) * LDT + lq * 8);
      bfr[i] = *(const bf16x8*)(Bs + (wn + i * 16 + lr) * LDT + lq * 8);
    }
    #pragma unroll
    for (int mt = 0; mt < 4; ++mt)
      #pragma unroll
      for (int nt = 0; nt < 4; ++nt)
        acc[mt][nt] = __builtin_amdgcn_mfma_f32_16x16x32_bf16(af[mt], bfr[nt], acc[mt][nt], 0, 0, 0);
  }
  #pragma unroll
  for (int nt = 0; nt < 4; ++nt) {
    int col = n0 + wn + nt * 16 + lr;
    float bias = b_ih[col] + b_hh[col];
    #pragma unroll
    for (int mt = 0; mt < 4; ++mt) {
      int rb = m0 + wm + mt * 16 + lq * 4;
      #pragma unroll
      for (int r = 0; r < 4; ++r)
        Cc[(size_t)(rb + r) * G4 + col] = acc[mt][nt][r] + bias;
    }
  }
}

// ---------------- phase 2: persistent step loop, per-group barriers ----------------
// 128 blocks x 512 thr (cooperative, 1 block/CU, 8 waves). Block: grp = bid&3
// (batches [16*grp,16*grp+16)), ublk = bid>>2 (hidden units [32*ublk,32*ublk+32)).
// Wave: wg = wave>>1 = gate (f,i,o,g), us = wave&1 = 16-unit sub-tile.
// W_hh fragments (wf[32], 128 VGPRs) are loaded ONCE per chunk and stay in
// registers (launch_bounds(512,1) -> 256 VGPR budget). xc is prefetched one
// step ahead. out stores are deferred past the barrier into the next step's
// stage window. Coherence design identical to R4 (verified):
//   - h history RING (slot dt = h(t0+dt)): no address read twice per kernel.
//   - h publish = no-return __hip_atomic_exchange (RMW at MALL, m20-verified);
//     drained by the vmcnt(0) before S3's s_barrier, before the arrival add.
//   - per-group epoch barrier: cumulative counter, atomicAdd arrivals,
//     sc0 sc1 spin load.
__global__ __launch_bounds__(512, 1) void lstm_steps_coop(
    const unsigned short* __restrict__ Whh,   // bf16 [4096][1024]
    const float* __restrict__ xc,             // chunk [64*TC][4096] fp32
    unsigned* __restrict__ hist32,            // h ring: (TC+1) x [64][1024] bf16
    float* __restrict__ c_state,              // fp32 [64][1024]
    float* __restrict__ out,                  // fp32 [64*512][1024]
    unsigned* __restrict__ bar,               // 4 counters, 128B apart
    int t0, int tc, int tclog2, int ep0) {
  __shared__ char hs[32768] __attribute__((aligned(16)));  // h tile [16][1024] bf16, swizzled
  __shared__ float gb[4][16][33];                          // activated gates (+1 pad)
  const int tid = threadIdx.x;
  const int bid = blockIdx.x;
  const int grp = bid & 3;
  const int U0 = (bid >> 2) * 32;
  const int wave = tid >> 6, lane = tid & 63;
  const int lq = lane >> 4, lr = lane & 15;
  const int wg = wave >> 1, us = wave & 1;
  const int rowbase = wg * HID + U0 + us * 16;             // gate-row block (in 4096)
  const unsigned short* wrow = Whh + (size_t)(rowbase + lr) * HID + lq * 8;
  // register-resident W fragments, loaded once per chunk (128 VGPRs)
  bf16x8 wf[32];
  #pragma unroll
  for (int kk = 0; kk < 32; ++kk) wf[kk] = *(const bf16x8*)(wrow + kk * 32);
  // stage mapping: thread covers row tid>>5, 4 x 16B slots 512B apart
  const int srow = tid >> 5, scq = tid & 31;
  const char* gsrc_base = (const char*)hist32 + (size_t)(grp * 16 + srow) * 2048 + scq * 16;
  const int lds_base = srow * 2048 + scq * 16;
  const int lswz = (srow & 7) << 4;
  // MFMA A-frag read base (same XOR per row)
  const int abase = lr * 2048 + lq * 16;
  const int aswz = (lr & 7) << 4;
  unsigned* barp = bar + grp * 32;
  // epilogue mapping: 1 cell/thread: batch eb, unit col U0+en
  const int eb = tid >> 5, en = tid & 31;
  const size_t cidx = (size_t)(grp * 16 + eb) * HID + U0 + en;
  const int hoff = (grp * 16 + eb) * 512 + ((U0 + en) >> 1);  // u32 idx in ring slot
  float c_val = c_state[cidx];
  float* const out_base = out + (size_t)(grp * 16 + eb) * T_STEPS * HID + U0 + en;
  // xc prefetch (step 0)
  const float* xcp = xc + (size_t)rowbase + lr;
  float xcv[4];
  #pragma unroll
  for (int r = 0; r < 4; ++r)
    xcv[r] = xcp[(size_t)(((grp * 16 + lq * 4 + r) << tclog2)) * G4];
  float out_prev = 0.f;
  int t_prev = -1;

  for (int dt = 0; dt < tc; ++dt) {
    const int t = t0 + dt;
    // ---- deferred out-store from previous step (overlaps stage latency) ----
    if (t_prev >= 0) out_base[(size_t)t_prev * HID] = out_prev;
    // ---- stage h(t) from ring slot dt into LDS ----
    {
      const char* src = gsrc_base + (size_t)dt * 131072;
      u32x4 v0, v1, v2, v3;
      asm volatile("global_load_dwordx4 %0, %1, off sc0 sc1" : "=v"(v0) : "v"(src +    0) : "memory");
      asm volatile("global_load_dwordx4 %0, %1, off sc0 sc1" : "=v"(v1) : "v"(src +  512) : "memory");
      asm volatile("global_load_dwordx4 %0, %1, off sc0 sc1" : "=v"(v2) : "v"(src + 1024) : "memory");
      asm volatile("global_load_dwordx4 %0, %1, off sc0 sc1" : "=v"(v3) : "v"(src + 1536) : "memory");
      asm volatile("s_waitcnt vmcnt(0)" ::: "memory");
      __builtin_amdgcn_sched_barrier(0);
      *(u32x4*)(hs + ((lds_base +    0) ^ lswz)) = v0;
      *(u32x4*)(hs + ((lds_base +  512) ^ lswz)) = v1;
      *(u32x4*)(hs + ((lds_base + 1024) ^ lswz)) = v2;
      *(u32x4*)(hs + ((lds_base + 1536) ^ lswz)) = v3;
    }
    __syncthreads();   // S1: h staged
    // ---- gate pre-activations: 32 MFMAs per wave, W from registers ----
    f32x4 accA = {}, accB = {};
    #pragma unroll
    for (int kk = 0; kk < 32; kk += 2) {
      bf16x8 a0 = *(const bf16x8*)(hs + ((abase + kk * 64) ^ aswz));
      bf16x8 a1 = *(const bf16x8*)(hs + ((abase + kk * 64 + 64) ^ aswz));
      accA = __builtin_amdgcn_mfma_f32_16x16x32_bf16(a0, wf[kk], accA, 0, 0, 0);
      accB = __builtin_amdgcn_mfma_f32_16x16x32_bf16(a1, wf[kk + 1], accB, 0, 0, 0);
    }
    f32x4 a = accA + accB;
    #pragma unroll
    for (int r = 0; r < 4; ++r) {
      float pre = a[r] + xcv[r];
      float v;
      if (wg == 3) v = 2.0f / (1.0f + __expf(-2.0f * pre)) - 1.0f;  // tanh
      else         v = 1.0f / (1.0f + __expf(-pre));                 // sigmoid
      gb[wg][lq * 4 + r][us * 16 + lr] = v;
    }
    __syncthreads();   // S2: gates ready
    // ---- prefetch next step's xc (latency hidden under epilogue+barrier) ----
    if (dt + 1 < tc) {
      #pragma unroll
      for (int r = 0; r < 4; ++r)
        xcv[r] = xcp[(size_t)(((grp * 16 + lq * 4 + r) << tclog2) + dt + 1) * G4];
    }
    // ---- cell update + h publish (atomic swap executes at MALL) ----
    {
      float f = gb[0][eb][en], i = gb[1][eb][en], o = gb[2][eb][en], gg = gb[3][eb][en];
      c_val = f * c_val + i * gg;
      float th = 2.0f / (1.0f + __expf(-2.0f * c_val)) - 1.0f;
      float h = o * th;
      out_prev = h; t_prev = t;
      float hn = __shfl_down(h, 1);
      if (!(en & 1)) {
        unsigned hv = pack2bf(h, hn);
        (void)__hip_atomic_exchange(hist32 + (size_t)(dt + 1) * 32768 + hoff, hv,
                                    __ATOMIC_RELAXED, __HIP_MEMORY_SCOPE_AGENT);
        if (dt == tc - 1)   // hand-off: next chunk reads its h(t0) from slot 0
          (void)__hip_atomic_exchange(hist32 + hoff, hv,
                                      __ATOMIC_RELAXED, __HIP_MEMORY_SCOPE_AGENT);
      }
    }
    if (dt != tc - 1) {
      __syncthreads();   // S3: exchanges drained (vmcnt(0) before s_barrier)
      // ---- per-group epoch barrier: 32 arrivals/step, cumulative count ----
      if (tid == 0) {
        atomicAdd(barp, 1u);
        const unsigned target = 32u * (unsigned)(ep0 + dt + 1);
        unsigned cnt;
        for (;;) {
          asm volatile("global_load_dword %0, %1, off sc0 sc1\n\ts_waitcnt vmcnt(0)"
                       : "=v"(cnt) : "v"(barp) : "memory");
          if (cnt >= target) break;
          __builtin_amdgcn_s_sleep(1);
        }
      }
      __syncthreads();   // S4: release
    }
  }
  out_base[(size_t)t_prev * HID] = out_prev;   // last step's deferred store
  c_state[cidx] = c_val;
}

extern "C" void kernel_launch(void* const* d_in, const int* in_sizes, int n_in,
                              void* d_out, int out_size, void* d_ws, size_t ws_size,
                              hipStream_t stream) {
  const float* x    = (const float*)d_in[0];
  const float* W_ih = (const float*)d_in[1];
  const float* W_hh = (const float*)d_in[2];
  const float* b_ih = (const float*)d_in[3];
  const float* b_hh = (const float*)d_in[4];
  float* out = (float*)d_out;
  char* ws = (char*)d_ws;

  const size_t whh_bytes = (size_t)G4 * HID * 2;     // 8 MB
  const size_t c_bytes   = (size_t)NB * HID * 4;     // 256 KB
  const size_t bar_bytes = 512;
  // adaptive time-chunk: largest TC in {64..4} s.t. chunk fp32 + h ring fit
  int tclog2 = 6;
  while (tclog2 > 1) {
    const size_t hist_b = ((size_t)(1 << tclog2) + 1) * (NB * HID * 2);
    size_t need = whh_bytes + c_bytes + bar_bytes + hist_b
                + (((size_t)NB << tclog2) * G4 * 4);
    if (need <= ws_size) break;
    --tclog2;
  }
  const int TC = 1 << tclog2;
  const size_t hist_bytes = ((size_t)TC + 1) * (NB * HID * 2);

  size_t off = 0;
  float* chunk = (float*)(ws + off);                  off += ((size_t)NB << tclog2) * G4 * 4;
  unsigned short* whhb = (unsigned short*)(ws + off); off += whh_bytes;
  float* c_state = (float*)(ws + off);                off += c_bytes;
  unsigned* hist32 = (unsigned*)(ws + off);           off += hist_bytes;
  unsigned* bar = (unsigned*)(ws + off);

  init_state_kernel<<<512, 256, 0, stream>>>(c_state, hist32, bar);
  cvt_bf16_kernel<<<4096, 256, 0, stream>>>((const float4*)W_hh, (ushort4*)whhb);

  const int n_chunks = T_STEPS >> tclog2;
  for (int c = 0; c < n_chunks; ++c) {
    const int t0 = c << tclog2;
    gemm_xproj_chunk<<<dim3(TC / 2, 32), 256, 0, stream>>>(x, W_ih, b_ih, b_hh,
                                                           chunk, t0, tclog2);
    int t0v = t0, tcv = TC, tlv = tclog2;
    int ep0 = c * (TC - 1);   // barriered steps before this chunk
    void* args[] = {(void*)&whhb, (void*)&chunk, (void*)&hist32, (void*)&c_state,
                    (void*)&out, (void*)&bar, (void*)&t0v, (void*)&tcv, (void*)&tlv,
                    (void*)&ep0};
    hipLaunchCooperativeKernel((const void*)lstm_steps_coop, dim3(128), dim3(512),
                               args, 0, stream);
  }
}